// Round 3
// baseline (235.200 us; speedup 1.0000x reference)
//
#include <hip/hip_runtime.h>
#include <stdint.h>

#define HD 512

typedef __bf16 bf16x8 __attribute__((ext_vector_type(8)));
typedef float  f32x4  __attribute__((ext_vector_type(4)));

union BF8U { uint4 u; bf16x8 v; };

__device__ __forceinline__ float fast_tanh(float x) {
  x = fminf(15.f, fmaxf(-15.f, x));
  float e = __expf(2.f * x);
  return (e - 1.f) * __builtin_amdgcn_rcpf(e + 1.f);
}
__device__ __forceinline__ float fast_sigmoid(float x) {
  return __builtin_amdgcn_rcpf(1.f + __expf(-x));
}

// ============ W prep: f32 [512][512] -> bf16 fragment-linear layout ============
// chunk (np,kt): dst[nt*512 + l*8 + jj] = W[kt*32 + (l>>4)*8 + jj][np*128 + nt*16 + (l&15)]
__global__ void prep_w_kernel(const float* __restrict__ W, unsigned short* __restrict__ Wb) {
  int chunk = blockIdx.x;            // 64 chunks
  int np = chunk >> 4, kt = chunk & 15;
  int t = threadIdx.x;               // 256 threads
  int jl = t & 127, kh = t >> 7;
  int j = np * 128 + jl;
  int nt = jl >> 4;
  unsigned short* base = Wb + (size_t)chunk * 4096 + nt * 512;
#pragma unroll
  for (int i = 0; i < 16; ++i) {
    int kk = kh * 16 + i;
    float v = W[(size_t)(kt * 32 + kk) * HD + j];   // coalesced across t
    int l = (kk >> 3) * 16 + (jl & 15);
    int jj = kk & 7;
    union { __bf16 h; unsigned short u; } cv;
    cv.h = (__bf16)v;
    base[l * 8 + jj] = cv.u;
  }
}

// ============ GEMM + tanh + v-dot -> partial logits ============
// ZERO-vmcnt-drain structure: B (pre-laid fragment-linear bf16) loaded DIRECTLY
// to registers per-wave (no LDS, no sync -- compiler inserts counted vmcnt at
// use). A staged f32->bf16 through 2x4KB swizzled LDS; per-iter sync is only
// s_waitcnt lgkmcnt(0) + raw s_barrier (A ds ops are ~30cyc; no global drain).
// A f32 prefetch 2-ahead in regs, B 1-ahead. 256 thr = 4 waves, tile 64x256.
__global__ __launch_bounds__(256, 3) void gemm_logit_kernel(
    const float* __restrict__ A, const unsigned short* __restrict__ Wb,
    const float* __restrict__ bias, const float* __restrict__ vvec,
    float* __restrict__ logit)
{
  int d = blockIdx.x;
  int xcd = d & 7, s = d >> 3;
  int c = s & 1, bm = (s >> 1) * 8 + xcd;      // c-pair blocks share bm & XCD -> A L2 reuse
  int tid = threadIdx.x, wave = tid >> 6, lane = tid & 63;
  int wn = wave;                                // 4 waves = 4 col-slices of 64
  size_t m0 = (size_t)bm * 64;

  // A: [2 buf][32 superrows][128 B] (superrow = 2 rows x 32 bf16, swizzled 16B slots)
  __shared__ __align__(16) char AshB[2][4096];

  // ---- A staging: thread t -> row = t>>2, k-granule q = t&3 (8 f32)
  const float* aSrc = A + (m0 + (tid >> 2)) * HD + (tid & 3) * 8;
  const int srW = tid >> 3;                    // superrow
  const int wA = srW * 128 + 16 * (((((tid >> 2) & 1) << 2) + (tid & 3)) ^ (srW & 7));

  // ---- B direct-load base: np = c*2 + (wn>>1), half = wn&1
  const char* srcB = (const char*)Wb + (size_t)(c * 2 + (wn >> 1)) * 131072 +
                     (wn & 1) * 4096 + lane * 16;

  // ---- A fragment read addr (row = mt*16 + (lane&15), k0 = (lane>>4)*8)
  const int aRd = ((lane & 15) >> 1) * 128 +
                  16 * ((4 * (lane & 1) + (lane >> 4)) ^ ((lane & 15) >> 1));

  float4 a4[2][2];             // 2-ahead f32 prefetch (data kt+2 loaded at iter kt)
  auto loadA = [&](float4 (&dst)[2], int kt) {
    const float* p = aSrc + kt * 32;
    dst[0] = *(const float4*)(p);
    dst[1] = *(const float4*)(p + 4);
  };
  auto writeA = [&](int buf, const float4 (&ar)[2]) {
    bf16x8 w0;
    w0[0] = (__bf16)ar[0].x; w0[1] = (__bf16)ar[0].y; w0[2] = (__bf16)ar[0].z; w0[3] = (__bf16)ar[0].w;
    w0[4] = (__bf16)ar[1].x; w0[5] = (__bf16)ar[1].y; w0[6] = (__bf16)ar[1].z; w0[7] = (__bf16)ar[1].w;
    *(bf16x8*)(&AshB[buf][0] + wA) = w0;
  };
  auto loadB = [&](bf16x8 (&dst)[4], int kt) {
    const char* sB = srcB + (size_t)kt * 8192;
#pragma unroll
    for (int ntl = 0; ntl < 4; ++ntl) {
      BF8U bu;
      bu.u = *(const uint4*)(sB + ntl * 1024);
      dst[ntl] = bu.v;
    }
  };

  f32x4 acc[4][4];
#pragma unroll
  for (int i = 0; i < 4; ++i)
#pragma unroll
    for (int j = 0; j < 4; ++j) acc[i][j] = (f32x4){0.f, 0.f, 0.f, 0.f};

  bf16x8 bA[4], bB[4];

  // prologue: A(0) into LDS buf0; B(0) in flight; A(1) f32 in flight
  {
    float4 t4[2];
    loadA(t4, 0);
    loadB(bA, 0);
    writeA(0, t4);           // compiler waits vmcnt on t4 only
    loadA(a4[0], 1);
    asm volatile("s_waitcnt lgkmcnt(0)" ::: "memory");
    __builtin_amdgcn_s_barrier();
  }

  auto body = [&](int kt, bf16x8 (&cur)[4], bf16x8 (&nxt)[4]) {
    if (kt < 15) loadB(nxt, kt + 1);                 // no sync ever needed for B
    if (kt < 14) loadA(a4[(kt + 1) & 1], kt + 2);    // consumed end of iter kt+1
    const char* aBuf = &AshB[kt & 1][0];
    bf16x8 af[4];
#pragma unroll
    for (int mt = 0; mt < 4; ++mt)
      af[mt] = *(const bf16x8*)(aBuf + mt * 1024 + aRd);
    __builtin_amdgcn_s_setprio(1);
#pragma unroll
    for (int mt = 0; mt < 4; ++mt)
#pragma unroll
      for (int ntl = 0; ntl < 4; ++ntl)
        acc[mt][ntl] = __builtin_amdgcn_mfma_f32_16x16x32_bf16(af[mt], cur[ntl], acc[mt][ntl], 0, 0, 0);
    __builtin_amdgcn_s_setprio(0);
    if (kt < 15) {
      writeA((kt + 1) & 1, a4[kt & 1]);              // a4 loaded 1.3 iters ago
      asm volatile("s_waitcnt lgkmcnt(0)" ::: "memory");  // publish A writes only
      __builtin_amdgcn_s_barrier();
    }
  };

#pragma unroll
  for (int kt = 0; kt < 16; kt += 2) {
    body(kt, bA, bB);
    body(kt + 1, bB, bA);
  }

  // ---- epilogue: tanh(acc+b)*v, reduce over columns, atomicAdd partial logit
  float part[4][4];
#pragma unroll
  for (int mt = 0; mt < 4; ++mt)
#pragma unroll
    for (int i = 0; i < 4; ++i) part[mt][i] = 0.f;

  const int colBase = c * 256 + wn * 64;
#pragma unroll
  for (int ntl = 0; ntl < 4; ++ntl) {
    int j = colBase + ntl * 16 + (lane & 15);
    float bj = bias[j], vj = vvec[j];
#pragma unroll
    for (int mt = 0; mt < 4; ++mt)
#pragma unroll
      for (int i = 0; i < 4; ++i)
        part[mt][i] += fast_tanh(acc[mt][ntl][i] + bj) * vj;
  }
#pragma unroll
  for (int off = 8; off >= 1; off >>= 1)
#pragma unroll
    for (int mt = 0; mt < 4; ++mt)
#pragma unroll
      for (int i = 0; i < 4; ++i)
        part[mt][i] += __shfl_xor(part[mt][i], off, 64);

  if ((lane & 15) == 0) {
    int rbase = (int)m0 + (lane >> 4) * 4;
#pragma unroll
    for (int mt = 0; mt < 4; ++mt)
#pragma unroll
      for (int i = 0; i < 4; ++i)
        atomicAdd(&logit[rbase + mt * 16 + i], part[mt][i]);
  }
}

// ============ segment bounds (sorted ids) ============
__global__ void seg_bounds_kernel(const int* __restrict__ seg, int* __restrict__ ss,
                                  int* __restrict__ se, int T) {
  int t = blockIdx.x * 256 + threadIdx.x;
  if (t >= T) return;
  int s = seg[t];
  if (t == 0 || seg[t - 1] != s) ss[s] = t;
  if (t == T - 1 || seg[t + 1] != s) se[s] = t + 1;
}

// ============ token softmax (masked) ============
__global__ void tok_softmax_kernel(const float* __restrict__ logit,
                                   const int* __restrict__ tl, float* __restrict__ w) {
  int b = blockIdx.x, tid = threadIdx.x;     // 512 threads
  bool i64 = (tl[1] == 0);
  int len = i64 ? tl[2 * b] : tl[b];
  float x = (tid < len) ? logit[b * 512 + tid] : -1e30f;
  float m = x;
#pragma unroll
  for (int off = 32; off; off >>= 1) m = fmaxf(m, __shfl_xor(m, off, 64));
  __shared__ float redm[8], reds[8];
  int wv = tid >> 6, ln = tid & 63;
  if (ln == 0) redm[wv] = m;
  __syncthreads();
  float bm = redm[0];
#pragma unroll
  for (int i = 1; i < 8; ++i) bm = fmaxf(bm, redm[i]);
  float e = (tid < len) ? __expf(x - bm) : 0.f;
  float s = e;
#pragma unroll
  for (int off = 32; off; off >>= 1) s += __shfl_xor(s, off, 64);
  if (ln == 0) reds[wv] = s;
  __syncthreads();
  float bs = 0.f;
#pragma unroll
  for (int i = 0; i < 8; ++i) bs += reds[i];
  w[b * 512 + tid] = e * __builtin_amdgcn_rcpf(bs);
}

// ============ AST segment softmax ============
__global__ void ast_softmax_kernel(const float* __restrict__ logit,
                                   const int* __restrict__ ss, const int* __restrict__ se,
                                   float* __restrict__ w) {
  int b = blockIdx.x, tid = threadIdx.x;     // 256 threads
  int t0 = ss[b], t1 = se[b];
  float m = -1e30f;
  for (int t = t0 + tid; t < t1; t += 256) m = fmaxf(m, logit[t]);
#pragma unroll
  for (int off = 32; off; off >>= 1) m = fmaxf(m, __shfl_xor(m, off, 64));
  __shared__ float redm[4], reds[4];
  int wv = tid >> 6, ln = tid & 63;
  if (ln == 0) redm[wv] = m;
  __syncthreads();
  float bm = fmaxf(fmaxf(redm[0], redm[1]), fmaxf(redm[2], redm[3]));
  float s = 0.f;
  for (int t = t0 + tid; t < t1; t += 256) s += __expf(logit[t] - bm);
#pragma unroll
  for (int off = 32; off; off >>= 1) s += __shfl_xor(s, off, 64);
  if (ln == 0) reds[wv] = s;
  __syncthreads();
  float bs = reds[0] + reds[1] + reds[2] + reds[3];
  float r = __builtin_amdgcn_rcpf(bs);
  for (int t = t0 + tid; t < t1; t += 256) w[t] = __expf(logit[t] - bm) * r;
}

// ============ pooling kernels (exact f32) ============
__global__ void pool_tok_kernel(const float* __restrict__ feat, const float* __restrict__ w,
                                float* __restrict__ pool) {
  int b = blockIdx.x, ch = blockIdx.y;       // 4 chunks x 128 s
  int tid = threadIdx.x;
  __shared__ float wsh[128];
  if (tid < 128) wsh[tid] = w[b * 512 + ch * 128 + tid];
  __syncthreads();
  int h = tid * 2;
  float2 acc = make_float2(0.f, 0.f);
  const float* fb = feat + ((size_t)b * 512 + ch * 128) * HD + h;
#pragma unroll 4
  for (int s = 0; s < 128; ++s) {
    float2 f = *(const float2*)(fb + (size_t)s * HD);
    acc.x += wsh[s] * f.x; acc.y += wsh[s] * f.y;
  }
  atomicAdd(&pool[b * 512 + h], acc.x);
  atomicAdd(&pool[b * 512 + h + 1], acc.y);
}

__global__ void pool_ast_kernel(const float* __restrict__ ast, const float* __restrict__ w,
                                const int* __restrict__ ss, const int* __restrict__ se,
                                float* __restrict__ pool) {
  int b = blockIdx.x, ch = blockIdx.y;       // 4 chunks
  int tid = threadIdx.x;
  int t0 = ss[b], t1 = se[b];
  int len = t1 - t0;
  if (len <= 0) return;
  int per = (len + 3) >> 2;
  int a0 = t0 + ch * per;
  int a1 = min(t1, a0 + per);
  __shared__ float wsh[128];
  int h = tid * 2;
  float2 acc = make_float2(0.f, 0.f);
  for (int base = a0; base < a1; base += 128) {
    int cnt = min(128, a1 - base);
    __syncthreads();
    if (tid < cnt) wsh[tid] = w[base + tid];
    __syncthreads();
    for (int s = 0; s < cnt; ++s) {
      float2 f = *(const float2*)(ast + (size_t)(base + s) * HD + h);
      acc.x += wsh[s] * f.x; acc.y += wsh[s] * f.y;
    }
  }
  atomicAdd(&pool[b * 512 + h], acc.x);
  atomicAdd(&pool[b * 512 + h + 1], acc.y);
}

__global__ void pool_cfg_kernel(const float* __restrict__ feat, const float* __restrict__ logit,
                                const int* __restrict__ mask, const float* __restrict__ cptr,
                                float* __restrict__ pool) {
  int b = blockIdx.x, ch = blockIdx.y;       // 2 chunks x 128 n
  int tid = threadIdx.x;
  float cc = cptr[0];
  __shared__ float gsh[128];
  int n0 = ch * 128;
  if (tid < 128) {
    int n = n0 + tid;
    float g = fast_sigmoid(logit[b * 256 + n] + cc);
    gsh[tid] = mask[b * 256 + n] ? g : 0.f;
  }
  __syncthreads();
  int h = tid * 2;
  float2 acc = make_float2(0.f, 0.f);
  const float* fb = feat + ((size_t)b * 256 + n0) * HD + h;
#pragma unroll 4
  for (int s = 0; s < 128; ++s) {
    float2 f = *(const float2*)(fb + (size_t)s * HD);
    acc.x += gsh[s] * f.x; acc.y += gsh[s] * f.y;
  }
  atomicAdd(&pool[b * 512 + h], acc.x);
  atomicAdd(&pool[b * 512 + h + 1], acc.y);
}

// ============ fusion: concat @ W_fuse, no atomics ============
__global__ void fuse_partial_kernel(const float* __restrict__ pools,   // [3][128][512]
                                    const float* __restrict__ Wf,
                                    float* __restrict__ fpart) {       // [12][128][512]
  int bg = blockIdx.x, kc = blockIdx.y;
  int tid = threadIdx.x;
  int bq = tid >> 7, jt = tid & 127;
  __shared__ float psh[8][128];
  for (int idx = tid; idx < 8 * 128; idx += 256) {
    int bb = idx >> 7, kk = idx & 127;
    int i = kc * 128 + kk;
    psh[bb][kk] = pools[(size_t)(i >> 9) * 65536 + (size_t)(bg * 8 + bb) * 512 + (i & 511)];
  }
  __syncthreads();
  f32x4 acc[4];
#pragma unroll
  for (int bb = 0; bb < 4; ++bb) acc[bb] = (f32x4){0.f, 0.f, 0.f, 0.f};
  const float* wrow = Wf + (size_t)(kc * 128) * 512 + jt * 4;
#pragma unroll 4
  for (int k = 0; k < 128; ++k) {
    float4 wv = *(const float4*)(wrow + (size_t)k * 512);
#pragma unroll
    for (int bb = 0; bb < 4; ++bb) {
      float p = psh[bq * 4 + bb][k];
      acc[bb][0] += p * wv.x; acc[bb][1] += p * wv.y;
      acc[bb][2] += p * wv.z; acc[bb][3] += p * wv.w;
    }
  }
  float* dst = fpart + (size_t)kc * 65536 + (size_t)(bg * 8 + bq * 4) * 512 + jt * 4;
#pragma unroll
  for (int bb = 0; bb < 4; ++bb)
    *(f32x4*)(dst + (size_t)bb * 512) = acc[bb];
}

__global__ void finalize_kernel(const float* __restrict__ fpart, const float* __restrict__ bfuse,
                                float* __restrict__ out) {
  int idx = blockIdx.x * 256 + threadIdx.x;  // 65536
  float s = bfuse[idx & 511];
#pragma unroll
  for (int kc = 0; kc < 12; ++kc) s += fpart[(size_t)kc * 65536 + idx];
  out[idx] = fast_tanh(s);
}

// ============ workspace layout (bytes) ============
static constexpr size_t OFF_WB_TOK = 0;
static constexpr size_t OFF_WB_AST = 512 * 1024;
static constexpr size_t OFF_WB_CFG = 1024 * 1024;
static constexpr size_t OFF_ZERO   = 1536 * 1024;
static constexpr size_t OFF_LG_TOK = OFF_ZERO;                       // 65536 f32
static constexpr size_t OFF_LG_AST = OFF_LG_TOK + 65536 * 4;         // 40960 f32
static constexpr size_t OFF_LG_CFG = OFF_LG_AST + 40960 * 4;         // 32768 f32
static constexpr size_t OFF_POOLS  = OFF_LG_CFG + 32768 * 4;         // 3*65536 f32
static constexpr size_t OFF_SS     = OFF_POOLS + 3 * 65536 * 4;      // 128 i32
static constexpr size_t OFF_SE     = OFF_SS + 512;
static constexpr size_t ZERO_BYTES = OFF_SE + 512 - OFF_ZERO;
static constexpr size_t OFF_W_TOK  = OFF_SE + 512;                   // 65536 f32
static constexpr size_t OFF_W_AST  = OFF_W_TOK + 65536 * 4;          // 40960 f32
static constexpr size_t OFF_FPART  = OFF_W_AST + 40960 * 4;          // 12*65536 f32

extern "C" void kernel_launch(void* const* d_in, const int* in_sizes, int n_in,
                              void* d_out, int out_size, void* d_ws, size_t ws_size,
                              hipStream_t stream) {
  const float* tok_feat = (const float*)d_in[0];
  const float* ast_h    = (const float*)d_in[1];
  const float* cfg_feat = (const float*)d_in[2];
  const float* W_tok = (const float*)d_in[3];
  const float* b_tok = (const float*)d_in[4];
  const float* v_tok = (const float*)d_in[5];
  const float* W_ast = (const float*)d_in[7];
  const float* b_ast = (const float*)d_in[8];
  const float* v_ast = (const float*)d_in[9];
  const float* W_cfg = (const float*)d_in[11];
  const float* b_cfg = (const float*)d_in[12];
  const float* v_cfg = (const float*)d_in[13];
  const float* c_cfg = (const float*)d_in[14];
  const float* W_fuse = (const float*)d_in[15];
  const float* b_fuse = (const float*)d_in[16];
  const int* tok_len  = (const int*)d_in[17];
  const int* node_seg = (const int*)d_in[18];
  const int* cfg_mask = (const int*)d_in[19];

  const int M_tok = in_sizes[0] / HD;   // 65536
  const int T_ast = in_sizes[1] / HD;   // 40960
  const int M_cfg = in_sizes[2] / HD;   // 32768

  char* ws = (char*)d_ws;
  unsigned short* wbTok = (unsigned short*)(ws + OFF_WB_TOK);
  unsigned short* wbAst = (unsigned short*)(ws + OFF_WB_AST);
  unsigned short* wbCfg = (unsigned short*)(ws + OFF_WB_CFG);
  float* lgTok = (float*)(ws + OFF_LG_TOK);
  float* lgAst = (float*)(ws + OFF_LG_AST);
  float* lgCfg = (float*)(ws + OFF_LG_CFG);
  float* pools = (float*)(ws + OFF_POOLS);
  int*   ss    = (int*)(ws + OFF_SS);
  int*   se    = (int*)(ws + OFF_SE);
  float* wTok  = (float*)(ws + OFF_W_TOK);
  float* wAst  = (float*)(ws + OFF_W_AST);
  float* fpart = (float*)(ws + OFF_FPART);

  // zero accumulators (logits, pools, seg bounds)
  hipMemsetAsync(ws + OFF_ZERO, 0, ZERO_BYTES, stream);

  // W -> bf16 fragment layout
  prep_w_kernel<<<64, 256, 0, stream>>>(W_tok, wbTok);
  prep_w_kernel<<<64, 256, 0, stream>>>(W_ast, wbAst);
  prep_w_kernel<<<64, 256, 0, stream>>>(W_cfg, wbCfg);
  seg_bounds_kernel<<<(T_ast + 255) / 256, 256, 0, stream>>>(node_seg, ss, se, T_ast);

  // ---- token modality (pool right after gemm: tok_feat still L3-resident)
  gemm_logit_kernel<<<(M_tok / 64) * 2, 256, 0, stream>>>(tok_feat, wbTok, b_tok, v_tok, lgTok);
  tok_softmax_kernel<<<128, 512, 0, stream>>>(lgTok, tok_len, wTok);
  pool_tok_kernel<<<dim3(128, 4), 256, 0, stream>>>(tok_feat, wTok, pools + 0 * 65536);

  // ---- AST modality
  gemm_logit_kernel<<<(T_ast / 64) * 2, 256, 0, stream>>>(ast_h, wbAst, b_ast, v_ast, lgAst);
  ast_softmax_kernel<<<128, 256, 0, stream>>>(lgAst, ss, se, wAst);
  pool_ast_kernel<<<dim3(128, 4), 256, 0, stream>>>(ast_h, wAst, ss, se, pools + 1 * 65536);

  // ---- CFG modality
  gemm_logit_kernel<<<(M_cfg / 64) * 2, 256, 0, stream>>>(cfg_feat, wbCfg, b_cfg, v_cfg, lgCfg);
  pool_cfg_kernel<<<dim3(128, 2), 256, 0, stream>>>(cfg_feat, lgCfg, cfg_mask, c_cfg, pools + 2 * 65536);

  // ---- fusion
  fuse_partial_kernel<<<dim3(16, 12), 256, 0, stream>>>(pools, W_fuse, fpart);
  finalize_kernel<<<256, 256, 0, stream>>>(fpart, b_fuse, (float*)d_out);
}

// Round 4
// 214.367 us; speedup vs baseline: 1.0972x; 1.0972x over previous
//
#include <hip/hip_runtime.h>
#include <stdint.h>

#define HD 512

typedef __bf16 bf16x8 __attribute__((ext_vector_type(8)));
typedef float  f32x4  __attribute__((ext_vector_type(4)));

union BF8U { uint4 u; bf16x8 v; };

__device__ __forceinline__ float fast_tanh(float x) {
  x = fminf(15.f, fmaxf(-15.f, x));
  float e = __expf(2.f * x);
  return (e - 1.f) * __builtin_amdgcn_rcpf(e + 1.f);
}
__device__ __forceinline__ float fast_sigmoid(float x) {
  return __builtin_amdgcn_rcpf(1.f + __expf(-x));
}

// ============ W prep (all 3 mats): f32 [512][512] -> bf16 fragment-linear ============
// chunk (np,kt): dst[nt*512 + l*8 + jj] = W[kt*32 + (l>>4)*8 + jj][np*128 + nt*16 + (l&15)]
__global__ void prep_w_kernel(const float* __restrict__ W0, const float* __restrict__ W1,
                              const float* __restrict__ W2, unsigned short* __restrict__ WbAll) {
  int mat = blockIdx.x >> 6;
  int chunk = blockIdx.x & 63;       // 64 chunks per matrix
  const float* W = (mat == 0) ? W0 : ((mat == 1) ? W1 : W2);
  int np = chunk >> 4, kt = chunk & 15;
  int t = threadIdx.x;               // 256 threads
  int jl = t & 127, kh = t >> 7;
  int j = np * 128 + jl;
  int nt = jl >> 4;
  unsigned short* base = WbAll + (size_t)mat * 262144 + (size_t)chunk * 4096 + nt * 512;
#pragma unroll
  for (int i = 0; i < 16; ++i) {
    int kk = kh * 16 + i;
    float v = W[(size_t)(kt * 32 + kk) * HD + j];   // coalesced across t
    int l = (kk >> 3) * 16 + (jl & 15);
    int jj = kk & 7;
    union { __bf16 h; unsigned short u; } cv;
    cv.h = (__bf16)v;
    base[l * 8 + jj] = cv.u;
  }
}

// ============ GEMM + tanh + v-dot -> partial logits ============
// Reg-B structure sized for 4 resident blocks/CU: total regs <= 128
// (acc 64 + af 16 + bf 16 + a4 8 + addressing). B (frag-linear bf16) loaded
// directly to regs each iter (single-buffered; ~200cyc L2 latency hidden by
// 4-block TLP). A staged f32->bf16 via 2x4KB swizzled LDS; per-iter sync is
// lgkmcnt(0)+s_barrier only -- NO vmcnt drain anywhere in the loop.
// 256 thr = 4 waves (4 col-slices of 64), tile 64 x 256.
__global__ __launch_bounds__(256, 4) void gemm_logit_kernel(
    const float* __restrict__ A, const unsigned short* __restrict__ Wb,
    const float* __restrict__ bias, const float* __restrict__ vvec,
    float* __restrict__ logit)
{
  int d = blockIdx.x;
  int xcd = d & 7, s = d >> 3;
  int c = s & 1, bm = (s >> 1) * 8 + xcd;      // c-pair blocks share bm & XCD -> A L2 reuse
  int tid = threadIdx.x, wave = tid >> 6, lane = tid & 63;
  int wn = wave;                                // 4 waves = 4 col-slices of 64
  size_t m0 = (size_t)bm * 64;

  // A: [2 buf][32 superrows][128 B] (superrow = 2 rows x 32 bf16, swizzled 16B slots)
  __shared__ __align__(16) char AshB[2][4096];

  // ---- A staging: thread t -> row = t>>2, k-granule q = t&3 (8 f32)
  const float* aSrc = A + (m0 + (tid >> 2)) * HD + (tid & 3) * 8;
  const int srW = tid >> 3;                    // superrow
  const int wA = srW * 128 + 16 * (((((tid >> 2) & 1) << 2) + (tid & 3)) ^ (srW & 7));

  // ---- B direct-load base: np = c*2 + (wn>>1), half = wn&1
  const char* srcB = (const char*)Wb + (size_t)(c * 2 + (wn >> 1)) * 131072 +
                     (wn & 1) * 4096 + lane * 16;

  // ---- A fragment read addr (row = mt*16 + (lane&15), k0 = (lane>>4)*8)
  const int aRd = ((lane & 15) >> 1) * 128 +
                  16 * ((4 * (lane & 1) + (lane >> 4)) ^ ((lane & 15) >> 1));

  float4 a4[2];                // 1-ahead f32 prefetch (one full iter of coverage)
  auto loadA = [&](float4 (&dst)[2], int kt) {
    const float* p = aSrc + kt * 32;
    dst[0] = *(const float4*)(p);
    dst[1] = *(const float4*)(p + 4);
  };
  auto writeA = [&](int buf, const float4 (&ar)[2]) {
    bf16x8 w0;
    w0[0] = (__bf16)ar[0].x; w0[1] = (__bf16)ar[0].y; w0[2] = (__bf16)ar[0].z; w0[3] = (__bf16)ar[0].w;
    w0[4] = (__bf16)ar[1].x; w0[5] = (__bf16)ar[1].y; w0[6] = (__bf16)ar[1].z; w0[7] = (__bf16)ar[1].w;
    *(bf16x8*)(&AshB[buf][0] + wA) = w0;
  };
  auto loadB = [&](bf16x8 (&dst)[4], int kt) {
    const char* sB = srcB + (size_t)kt * 8192;
#pragma unroll
    for (int ntl = 0; ntl < 4; ++ntl) {
      BF8U bu;
      bu.u = *(const uint4*)(sB + ntl * 1024);
      dst[ntl] = bu.v;
    }
  };

  f32x4 acc[4][4];
#pragma unroll
  for (int i = 0; i < 4; ++i)
#pragma unroll
    for (int j = 0; j < 4; ++j) acc[i][j] = (f32x4){0.f, 0.f, 0.f, 0.f};

  // prologue: A(0) -> LDS buf0; A(1) f32 left in flight across the barrier
  {
    float4 t4[2];
    loadA(t4, 0);
    writeA(0, t4);           // compiler inserts counted vmcnt wait on t4 only
    loadA(a4, 1);
    asm volatile("s_waitcnt lgkmcnt(0)" ::: "memory");
    __builtin_amdgcn_s_barrier();
  }

  bf16x8 bf[4];
#pragma unroll 2
  for (int kt = 0; kt < 16; ++kt) {
    loadB(bf, kt);                               // consumed this iter (counted wait at MFMA)
    const char* aBuf = &AshB[kt & 1][0];
    bf16x8 af[4];
#pragma unroll
    for (int mt = 0; mt < 4; ++mt)
      af[mt] = *(const bf16x8*)(aBuf + mt * 1024 + aRd);
    __builtin_amdgcn_s_setprio(1);
#pragma unroll
    for (int mt = 0; mt < 4; ++mt)
#pragma unroll
      for (int ntl = 0; ntl < 4; ++ntl)
        acc[mt][ntl] = __builtin_amdgcn_mfma_f32_16x16x32_bf16(af[mt], bf[ntl], acc[mt][ntl], 0, 0, 0);
    __builtin_amdgcn_s_setprio(0);
    if (kt < 15) {
      writeA((kt + 1) & 1, a4);                  // consumes data(kt+1), loaded 1 iter ago
      if (kt < 14) loadA(a4, kt + 2);            // full-iter coverage
      asm volatile("s_waitcnt lgkmcnt(0)" ::: "memory");  // publish A ds_writes only
      __builtin_amdgcn_s_barrier();
    }
  }

  // ---- epilogue: tanh(acc+b)*v, reduce over columns, atomicAdd partial logit
  float part[4][4];
#pragma unroll
  for (int mt = 0; mt < 4; ++mt)
#pragma unroll
    for (int i = 0; i < 4; ++i) part[mt][i] = 0.f;

  const int colBase = c * 256 + wn * 64;
#pragma unroll
  for (int ntl = 0; ntl < 4; ++ntl) {
    int j = colBase + ntl * 16 + (lane & 15);
    float bj = bias[j], vj = vvec[j];
#pragma unroll
    for (int mt = 0; mt < 4; ++mt)
#pragma unroll
      for (int i = 0; i < 4; ++i)
        part[mt][i] += fast_tanh(acc[mt][ntl][i] + bj) * vj;
  }
#pragma unroll
  for (int off = 8; off >= 1; off >>= 1)
#pragma unroll
    for (int mt = 0; mt < 4; ++mt)
#pragma unroll
      for (int i = 0; i < 4; ++i)
        part[mt][i] += __shfl_xor(part[mt][i], off, 64);

  if ((lane & 15) == 0) {
    int rbase = (int)m0 + (lane >> 4) * 4;
#pragma unroll
    for (int mt = 0; mt < 4; ++mt)
#pragma unroll
      for (int i = 0; i < 4; ++i)
        atomicAdd(&logit[rbase + mt * 16 + i], part[mt][i]);
  }
}

// ============ segment bounds (sorted ids) ============
__global__ void seg_bounds_kernel(const int* __restrict__ seg, int* __restrict__ ss,
                                  int* __restrict__ se, int T) {
  int t = blockIdx.x * 256 + threadIdx.x;
  if (t >= T) return;
  int s = seg[t];
  if (t == 0 || seg[t - 1] != s) ss[s] = t;
  if (t == T - 1 || seg[t + 1] != s) se[s] = t + 1;
}

// ============ pool_tok: fused masked softmax + pooling ============
__global__ void pool_tok_kernel(const float* __restrict__ feat, const float* __restrict__ logit,
                                const int* __restrict__ tl, float* __restrict__ pool) {
  int b = blockIdx.x, ch = blockIdx.y;       // 4 chunks x 128 s
  int tid = threadIdx.x;                     // 256 threads
  bool i64 = (tl[1] == 0);
  int len = i64 ? tl[2 * b] : tl[b];
  const float* lg = logit + b * 512;
  // block softmax denominators over the full row (each block recomputes: cheap)
  float x0 = (tid < len) ? lg[tid] : -1e30f;
  float x1 = (tid + 256 < len) ? lg[tid + 256] : -1e30f;
  float m = fmaxf(x0, x1);
#pragma unroll
  for (int off = 32; off; off >>= 1) m = fmaxf(m, __shfl_xor(m, off, 64));
  __shared__ float redm[4], reds[4];
  int wv = tid >> 6, ln = tid & 63;
  if (ln == 0) redm[wv] = m;
  __syncthreads();
  float bm = fmaxf(fmaxf(redm[0], redm[1]), fmaxf(redm[2], redm[3]));
  float s = ((tid < len) ? __expf(x0 - bm) : 0.f) + ((tid + 256 < len) ? __expf(x1 - bm) : 0.f);
#pragma unroll
  for (int off = 32; off; off >>= 1) s += __shfl_xor(s, off, 64);
  if (ln == 0) reds[wv] = s;
  __syncthreads();
  float bs = reds[0] + reds[1] + reds[2] + reds[3];
  float rb = __builtin_amdgcn_rcpf(bs);
  __shared__ float wsh[128];
  if (tid < 128) {
    int sidx = ch * 128 + tid;
    wsh[tid] = (sidx < len) ? __expf(lg[sidx] - bm) * rb : 0.f;
  }
  __syncthreads();
  int h = tid * 2;
  float2 acc = make_float2(0.f, 0.f);
  const float* fb = feat + ((size_t)b * 512 + ch * 128) * HD + h;
#pragma unroll 4
  for (int s2 = 0; s2 < 128; ++s2) {
    float2 f = *(const float2*)(fb + (size_t)s2 * HD);
    acc.x += wsh[s2] * f.x; acc.y += wsh[s2] * f.y;
  }
  atomicAdd(&pool[b * 512 + h], acc.x);
  atomicAdd(&pool[b * 512 + h + 1], acc.y);
}

// ============ pool_ast: fused segment softmax + pooling ============
__global__ void pool_ast_kernel(const float* __restrict__ ast, const float* __restrict__ logit,
                                const int* __restrict__ ss, const int* __restrict__ se,
                                float* __restrict__ pool) {
  int b = blockIdx.x, ch = blockIdx.y;       // 4 chunks
  int tid = threadIdx.x;                     // 256 threads
  int t0 = ss[b], t1 = se[b];
  int len = t1 - t0;
  if (len <= 0) return;
  float m = -1e30f;
  for (int t = t0 + tid; t < t1; t += 256) m = fmaxf(m, logit[t]);
#pragma unroll
  for (int off = 32; off; off >>= 1) m = fmaxf(m, __shfl_xor(m, off, 64));
  __shared__ float redm[4], reds[4];
  int wv = tid >> 6, ln = tid & 63;
  if (ln == 0) redm[wv] = m;
  __syncthreads();
  float bm = fmaxf(fmaxf(redm[0], redm[1]), fmaxf(redm[2], redm[3]));
  float s = 0.f;
  for (int t = t0 + tid; t < t1; t += 256) s += __expf(logit[t] - bm);
#pragma unroll
  for (int off = 32; off; off >>= 1) s += __shfl_xor(s, off, 64);
  if (ln == 0) reds[wv] = s;
  __syncthreads();
  float bs = reds[0] + reds[1] + reds[2] + reds[3];
  float r = __builtin_amdgcn_rcpf(bs);
  int per = (len + 3) >> 2;
  int a0 = t0 + ch * per;
  int a1 = min(t1, a0 + per);
  __shared__ float wsh[128];
  int h = tid * 2;
  float2 acc = make_float2(0.f, 0.f);
  for (int base = a0; base < a1; base += 128) {
    int cnt = min(128, a1 - base);
    __syncthreads();
    if (tid < cnt) wsh[tid] = __expf(logit[base + tid] - bm) * r;
    __syncthreads();
    for (int s2 = 0; s2 < cnt; ++s2) {
      float2 f = *(const float2*)(ast + (size_t)(base + s2) * HD + h);
      acc.x += wsh[s2] * f.x; acc.y += wsh[s2] * f.y;
    }
  }
  atomicAdd(&pool[b * 512 + h], acc.x);
  atomicAdd(&pool[b * 512 + h + 1], acc.y);
}

__global__ void pool_cfg_kernel(const float* __restrict__ feat, const float* __restrict__ logit,
                                const int* __restrict__ mask, const float* __restrict__ cptr,
                                float* __restrict__ pool) {
  int b = blockIdx.x, ch = blockIdx.y;       // 2 chunks x 128 n
  int tid = threadIdx.x;
  float cc = cptr[0];
  __shared__ float gsh[128];
  int n0 = ch * 128;
  if (tid < 128) {
    int n = n0 + tid;
    float g = fast_sigmoid(logit[b * 256 + n] + cc);
    gsh[tid] = mask[b * 256 + n] ? g : 0.f;
  }
  __syncthreads();
  int h = tid * 2;
  float2 acc = make_float2(0.f, 0.f);
  const float* fb = feat + ((size_t)b * 256 + n0) * HD + h;
#pragma unroll 4
  for (int s = 0; s < 128; ++s) {
    float2 f = *(const float2*)(fb + (size_t)s * HD);
    acc.x += gsh[s] * f.x; acc.y += gsh[s] * f.y;
  }
  atomicAdd(&pool[b * 512 + h], acc.x);
  atomicAdd(&pool[b * 512 + h + 1], acc.y);
}

// ============ fusion: concat @ W_fuse, no atomics ============
__global__ void fuse_partial_kernel(const float* __restrict__ pools,   // [3][128][512]
                                    const float* __restrict__ Wf,
                                    float* __restrict__ fpart) {       // [12][128][512]
  int bg = blockIdx.x, kc = blockIdx.y;
  int tid = threadIdx.x;
  int bq = tid >> 7, jt = tid & 127;
  __shared__ float psh[8][128];
  for (int idx = tid; idx < 8 * 128; idx += 256) {
    int bb = idx >> 7, kk = idx & 127;
    int i = kc * 128 + kk;
    psh[bb][kk] = pools[(size_t)(i >> 9) * 65536 + (size_t)(bg * 8 + bb) * 512 + (i & 511)];
  }
  __syncthreads();
  f32x4 acc[4];
#pragma unroll
  for (int bb = 0; bb < 4; ++bb) acc[bb] = (f32x4){0.f, 0.f, 0.f, 0.f};
  const float* wrow = Wf + (size_t)(kc * 128) * 512 + jt * 4;
#pragma unroll 4
  for (int k = 0; k < 128; ++k) {
    float4 wv = *(const float4*)(wrow + (size_t)k * 512);
#pragma unroll
    for (int bb = 0; bb < 4; ++bb) {
      float p = psh[bq * 4 + bb][k];
      acc[bb][0] += p * wv.x; acc[bb][1] += p * wv.y;
      acc[bb][2] += p * wv.z; acc[bb][3] += p * wv.w;
    }
  }
  float* dst = fpart + (size_t)kc * 65536 + (size_t)(bg * 8 + bq * 4) * 512 + jt * 4;
#pragma unroll
  for (int bb = 0; bb < 4; ++bb)
    *(f32x4*)(dst + (size_t)bb * 512) = acc[bb];
}

__global__ void finalize_kernel(const float* __restrict__ fpart, const float* __restrict__ bfuse,
                                float* __restrict__ out) {
  int idx = blockIdx.x * 256 + threadIdx.x;  // 65536
  float s = bfuse[idx & 511];
#pragma unroll
  for (int kc = 0; kc < 12; ++kc) s += fpart[(size_t)kc * 65536 + idx];
  out[idx] = fast_tanh(s);
}

// ============ workspace layout (bytes) ============
static constexpr size_t OFF_WB_TOK = 0;
static constexpr size_t OFF_WB_AST = 512 * 1024;
static constexpr size_t OFF_WB_CFG = 1024 * 1024;
static constexpr size_t OFF_ZERO   = 1536 * 1024;
static constexpr size_t OFF_LG_TOK = OFF_ZERO;                       // 65536 f32
static constexpr size_t OFF_LG_AST = OFF_LG_TOK + 65536 * 4;         // 40960 f32
static constexpr size_t OFF_LG_CFG = OFF_LG_AST + 40960 * 4;         // 32768 f32
static constexpr size_t OFF_POOLS  = OFF_LG_CFG + 32768 * 4;         // 3*65536 f32
static constexpr size_t OFF_SS     = OFF_POOLS + 3 * 65536 * 4;      // 128 i32
static constexpr size_t OFF_SE     = OFF_SS + 512;
static constexpr size_t ZERO_BYTES = OFF_SE + 512 - OFF_ZERO;
static constexpr size_t OFF_FPART  = OFF_SE + 512;                   // 12*65536 f32

extern "C" void kernel_launch(void* const* d_in, const int* in_sizes, int n_in,
                              void* d_out, int out_size, void* d_ws, size_t ws_size,
                              hipStream_t stream) {
  const float* tok_feat = (const float*)d_in[0];
  const float* ast_h    = (const float*)d_in[1];
  const float* cfg_feat = (const float*)d_in[2];
  const float* W_tok = (const float*)d_in[3];
  const float* b_tok = (const float*)d_in[4];
  const float* v_tok = (const float*)d_in[5];
  const float* W_ast = (const float*)d_in[7];
  const float* b_ast = (const float*)d_in[8];
  const float* v_ast = (const float*)d_in[9];
  const float* W_cfg = (const float*)d_in[11];
  const float* b_cfg = (const float*)d_in[12];
  const float* v_cfg = (const float*)d_in[13];
  const float* c_cfg = (const float*)d_in[14];
  const float* W_fuse = (const float*)d_in[15];
  const float* b_fuse = (const float*)d_in[16];
  const int* tok_len  = (const int*)d_in[17];
  const int* node_seg = (const int*)d_in[18];
  const int* cfg_mask = (const int*)d_in[19];

  const int M_tok = in_sizes[0] / HD;   // 65536
  const int T_ast = in_sizes[1] / HD;   // 40960
  const int M_cfg = in_sizes[2] / HD;   // 32768

  char* ws = (char*)d_ws;
  unsigned short* wbAll = (unsigned short*)(ws + OFF_WB_TOK);
  unsigned short* wbTok = (unsigned short*)(ws + OFF_WB_TOK);
  unsigned short* wbAst = (unsigned short*)(ws + OFF_WB_AST);
  unsigned short* wbCfg = (unsigned short*)(ws + OFF_WB_CFG);
  float* lgTok = (float*)(ws + OFF_LG_TOK);
  float* lgAst = (float*)(ws + OFF_LG_AST);
  float* lgCfg = (float*)(ws + OFF_LG_CFG);
  float* pools = (float*)(ws + OFF_POOLS);
  int*   ss    = (int*)(ws + OFF_SS);
  int*   se    = (int*)(ws + OFF_SE);
  float* fpart = (float*)(ws + OFF_FPART);

  // zero accumulators (logits, pools, seg bounds)
  hipMemsetAsync(ws + OFF_ZERO, 0, ZERO_BYTES, stream);

  // W -> bf16 fragment layout (all 3 matrices, one dispatch)
  prep_w_kernel<<<192, 256, 0, stream>>>(W_tok, W_ast, W_cfg, wbAll);
  seg_bounds_kernel<<<(T_ast + 255) / 256, 256, 0, stream>>>(node_seg, ss, se, T_ast);

  // ---- token modality (pool right after gemm: tok_feat still L3-resident)
  gemm_logit_kernel<<<(M_tok / 64) * 2, 256, 0, stream>>>(tok_feat, wbTok, b_tok, v_tok, lgTok);
  pool_tok_kernel<<<dim3(128, 4), 256, 0, stream>>>(tok_feat, lgTok, tok_len, pools + 0 * 65536);

  // ---- AST modality
  gemm_logit_kernel<<<(T_ast / 64) * 2, 256, 0, stream>>>(ast_h, wbAst, b_ast, v_ast, lgAst);
  pool_ast_kernel<<<dim3(128, 4), 256, 0, stream>>>(ast_h, lgAst, ss, se, pools + 1 * 65536);

  // ---- CFG modality
  gemm_logit_kernel<<<(M_cfg / 64) * 2, 256, 0, stream>>>(cfg_feat, wbCfg, b_cfg, v_cfg, lgCfg);
  pool_cfg_kernel<<<dim3(128, 2), 256, 0, stream>>>(cfg_feat, lgCfg, cfg_mask, c_cfg, pools + 2 * 65536);

  // ---- fusion
  fuse_partial_kernel<<<dim3(16, 12), 256, 0, stream>>>(pools, W_fuse, fpart);
  finalize_kernel<<<256, 256, 0, stream>>>(fpart, b_fuse, (float*)d_out);
}

// Round 5
// 211.268 us; speedup vs baseline: 1.1133x; 1.0147x over previous
//
#include <hip/hip_runtime.h>
#include <stdint.h>

#define HD 512

typedef __bf16 bf16x8 __attribute__((ext_vector_type(8)));
typedef __bf16 bf16x4 __attribute__((ext_vector_type(4)));
typedef float  f32x4  __attribute__((ext_vector_type(4)));

union BF8U { uint4 u; bf16x8 v; };

__device__ __forceinline__ float fast_tanh(float x) {
  x = fminf(15.f, fmaxf(-15.f, x));
  float e = __expf(2.f * x);
  return (e - 1.f) * __builtin_amdgcn_rcpf(e + 1.f);
}
__device__ __forceinline__ float fast_sigmoid(float x) {
  return __builtin_amdgcn_rcpf(1.f + __expf(-x));
}

// ============ W prep (all 3 mats): f32 [512][512] -> bf16 fragment-linear ============
// chunk (np,kt): dst[nt*512 + l*8 + jj] = W[kt*32 + (l>>4)*8 + jj][np*128 + nt*16 + (l&15)]
__global__ void prep_w_kernel(const float* __restrict__ W0, const float* __restrict__ W1,
                              const float* __restrict__ W2, unsigned short* __restrict__ WbAll) {
  int mat = blockIdx.x >> 6;
  int chunk = blockIdx.x & 63;       // 64 chunks per matrix
  const float* W = (mat == 0) ? W0 : ((mat == 1) ? W1 : W2);
  int np = chunk >> 4, kt = chunk & 15;
  int t = threadIdx.x;               // 256 threads
  int jl = t & 127, kh = t >> 7;
  int j = np * 128 + jl;
  int nt = jl >> 4;
  unsigned short* base = WbAll + (size_t)mat * 262144 + (size_t)chunk * 4096 + nt * 512;
#pragma unroll
  for (int i = 0; i < 16; ++i) {
    int kk = kh * 16 + i;
    float v = W[(size_t)(kt * 32 + kk) * HD + j];   // coalesced across t
    int l = (kk >> 3) * 16 + (jl & 15);
    int jj = kk & 7;
    union { __bf16 h; unsigned short u; } cv;
    cv.h = (__bf16)v;
    base[l * 8 + jj] = cv.u;
  }
}

// ============ GEMM + tanh + v-dot -> partial logits ============
// FULL-COLUMN blocks: 512 thr = 8 waves, tile 64 rows x 512 cols -> each A
// row-panel streams through L2/L3 EXACTLY ONCE (the R2/R4 invariant was A-path
// traffic, not sync structure). Per wave: 64x64 output (acc 64 VGPR), own
// 64-col slice of frag-linear Wb loaded reg-direct from L2 (no LDS, no sync).
// A staged f32->bf16 via 2x4KB swizzled LDS, 1-ahead reg prefetch; per-iter
// sync = lgkmcnt(0) + s_barrier only (no vmcnt drain anywhere).
__global__ __launch_bounds__(512, 2) void gemm_logit_kernel(
    const float* __restrict__ A, const unsigned short* __restrict__ Wb,
    const float* __restrict__ bias, const float* __restrict__ vvec,
    float* __restrict__ logit)
{
  int bm = blockIdx.x;
  int tid = threadIdx.x, wave = tid >> 6, lane = tid & 63;
  int wn = wave;                                // 8 waves = 8 col-slices of 64
  size_t m0 = (size_t)bm * 64;

  // A: [2 buf][32 superrows][128 B] (superrow = 2 rows x 32 bf16, swizzled 16B slots)
  __shared__ __align__(16) char AshB[2][4096];

  // ---- A staging: thread t -> row = t>>3, granule q = t&7 (4 f32 = 16B)
  const float* aSrc = A + (m0 + (tid >> 3)) * HD + (tid & 7) * 4;
  // LDS write addr (8B per thread): sr = row>>1, slot = (row&1)*4 + (q>>1), half = q&1
  const int rowS = tid >> 3, qS = tid & 7;
  const int srW = rowS >> 1;
  const int wA = srW * 128 + 16 * ((((rowS & 1) << 2) + (qS >> 1)) ^ (srW & 7)) + (qS & 1) * 8;

  // ---- B direct-load base: np = wn>>1, half = wn&1 (global col base = wn*64)
  const char* srcB = (const char*)Wb + (size_t)(wn >> 1) * 131072 +
                     (wn & 1) * 4096 + lane * 16;

  // ---- A fragment read addr (row = mt*16 + (lane&15), k0 = (lane>>4)*8)
  const int aRd = ((lane & 15) >> 1) * 128 +
                  16 * ((4 * (lane & 1) + (lane >> 4)) ^ ((lane & 15) >> 1));

  float4 a4;                   // 1-ahead f32 prefetch (one full iter of coverage)
  auto loadA = [&](float4& dst, int kt) {
    dst = *(const float4*)(aSrc + kt * 32);
  };
  auto writeA = [&](int buf, const float4& ar) {
    bf16x4 w0;
    w0[0] = (__bf16)ar.x; w0[1] = (__bf16)ar.y; w0[2] = (__bf16)ar.z; w0[3] = (__bf16)ar.w;
    *(bf16x4*)(&AshB[buf][0] + wA) = w0;
  };
  auto loadB = [&](bf16x8 (&dst)[4], int kt) {
    const char* sB = srcB + (size_t)kt * 8192;
#pragma unroll
    for (int ntl = 0; ntl < 4; ++ntl) {
      BF8U bu;
      bu.u = *(const uint4*)(sB + ntl * 1024);
      dst[ntl] = bu.v;
    }
  };

  f32x4 acc[4][4];
#pragma unroll
  for (int i = 0; i < 4; ++i)
#pragma unroll
    for (int j = 0; j < 4; ++j) acc[i][j] = (f32x4){0.f, 0.f, 0.f, 0.f};

  // prologue: A(0) -> LDS buf0; A(1) f32 left in flight across the barrier
  {
    float4 t4;
    loadA(t4, 0);
    writeA(0, t4);           // compiler inserts counted vmcnt wait on t4 only
    loadA(a4, 1);
    asm volatile("s_waitcnt lgkmcnt(0)" ::: "memory");
    __builtin_amdgcn_s_barrier();
  }

  bf16x8 bf[4];
#pragma unroll 2
  for (int kt = 0; kt < 16; ++kt) {
    loadB(bf, kt);                               // consumed this iter (counted wait at MFMA)
    const char* aBuf = &AshB[kt & 1][0];
    bf16x8 af[4];
#pragma unroll
    for (int mt = 0; mt < 4; ++mt)
      af[mt] = *(const bf16x8*)(aBuf + mt * 1024 + aRd);
#pragma unroll
    for (int mt = 0; mt < 4; ++mt)
#pragma unroll
      for (int ntl = 0; ntl < 4; ++ntl)
        acc[mt][ntl] = __builtin_amdgcn_mfma_f32_16x16x32_bf16(af[mt], bf[ntl], acc[mt][ntl], 0, 0, 0);
    if (kt < 15) {
      writeA((kt + 1) & 1, a4);                  // consumes data(kt+1), loaded 1 iter ago
      if (kt < 14) loadA(a4, kt + 2);            // full-iter coverage
      asm volatile("s_waitcnt lgkmcnt(0)" ::: "memory");  // publish A ds_writes only
      __builtin_amdgcn_s_barrier();
    }
  }

  // ---- epilogue: tanh(acc+b)*v, reduce over columns, atomicAdd partial logit
  float part[4][4];
#pragma unroll
  for (int mt = 0; mt < 4; ++mt)
#pragma unroll
    for (int i = 0; i < 4; ++i) part[mt][i] = 0.f;

  const int colBase = wn * 64;
#pragma unroll
  for (int ntl = 0; ntl < 4; ++ntl) {
    int j = colBase + ntl * 16 + (lane & 15);
    float bj = bias[j], vj = vvec[j];
#pragma unroll
    for (int mt = 0; mt < 4; ++mt)
#pragma unroll
      for (int i = 0; i < 4; ++i)
        part[mt][i] += fast_tanh(acc[mt][ntl][i] + bj) * vj;
  }
#pragma unroll
  for (int off = 8; off >= 1; off >>= 1)
#pragma unroll
    for (int mt = 0; mt < 4; ++mt)
#pragma unroll
      for (int i = 0; i < 4; ++i)
        part[mt][i] += __shfl_xor(part[mt][i], off, 64);

  if ((lane & 15) == 0) {
    int rbase = (int)m0 + (lane >> 4) * 4;
#pragma unroll
    for (int mt = 0; mt < 4; ++mt)
#pragma unroll
      for (int i = 0; i < 4; ++i)
        atomicAdd(&logit[rbase + mt * 16 + i], part[mt][i]);
  }
}

// ============ segment bounds (sorted ids) ============
__global__ void seg_bounds_kernel(const int* __restrict__ seg, int* __restrict__ ss,
                                  int* __restrict__ se, int T) {
  int t = blockIdx.x * 256 + threadIdx.x;
  if (t >= T) return;
  int s = seg[t];
  if (t == 0 || seg[t - 1] != s) ss[s] = t;
  if (t == T - 1 || seg[t + 1] != s) se[s] = t + 1;
}

// ============ pool_tok: fused masked softmax + pooling ============
__global__ void pool_tok_kernel(const float* __restrict__ feat, const float* __restrict__ logit,
                                const int* __restrict__ tl, float* __restrict__ pool) {
  int b = blockIdx.x, ch = blockIdx.y;       // 4 chunks x 128 s
  int tid = threadIdx.x;                     // 256 threads
  bool i64 = (tl[1] == 0);
  int len = i64 ? tl[2 * b] : tl[b];
  const float* lg = logit + b * 512;
  // block softmax denominators over the full row (each block recomputes: cheap)
  float x0 = (tid < len) ? lg[tid] : -1e30f;
  float x1 = (tid + 256 < len) ? lg[tid + 256] : -1e30f;
  float m = fmaxf(x0, x1);
#pragma unroll
  for (int off = 32; off; off >>= 1) m = fmaxf(m, __shfl_xor(m, off, 64));
  __shared__ float redm[4], reds[4];
  int wv = tid >> 6, ln = tid & 63;
  if (ln == 0) redm[wv] = m;
  __syncthreads();
  float bm = fmaxf(fmaxf(redm[0], redm[1]), fmaxf(redm[2], redm[3]));
  float s = ((tid < len) ? __expf(x0 - bm) : 0.f) + ((tid + 256 < len) ? __expf(x1 - bm) : 0.f);
#pragma unroll
  for (int off = 32; off; off >>= 1) s += __shfl_xor(s, off, 64);
  if (ln == 0) reds[wv] = s;
  __syncthreads();
  float bs = reds[0] + reds[1] + reds[2] + reds[3];
  float rb = __builtin_amdgcn_rcpf(bs);
  __shared__ float wsh[128];
  if (tid < 128) {
    int sidx = ch * 128 + tid;
    wsh[tid] = (sidx < len) ? __expf(lg[sidx] - bm) * rb : 0.f;
  }
  __syncthreads();
  int h = tid * 2;
  float2 acc = make_float2(0.f, 0.f);
  const float* fb = feat + ((size_t)b * 512 + ch * 128) * HD + h;
#pragma unroll 4
  for (int s2 = 0; s2 < 128; ++s2) {
    float2 f = *(const float2*)(fb + (size_t)s2 * HD);
    acc.x += wsh[s2] * f.x; acc.y += wsh[s2] * f.y;
  }
  atomicAdd(&pool[b * 512 + h], acc.x);
  atomicAdd(&pool[b * 512 + h + 1], acc.y);
}

// ============ pool_ast: fused segment softmax + pooling ============
__global__ void pool_ast_kernel(const float* __restrict__ ast, const float* __restrict__ logit,
                                const int* __restrict__ ss, const int* __restrict__ se,
                                float* __restrict__ pool) {
  int b = blockIdx.x, ch = blockIdx.y;       // 4 chunks
  int tid = threadIdx.x;                     // 256 threads
  int t0 = ss[b], t1 = se[b];
  int len = t1 - t0;
  if (len <= 0) return;
  float m = -1e30f;
  for (int t = t0 + tid; t < t1; t += 256) m = fmaxf(m, logit[t]);
#pragma unroll
  for (int off = 32; off; off >>= 1) m = fmaxf(m, __shfl_xor(m, off, 64));
  __shared__ float redm[4], reds[4];
  int wv = tid >> 6, ln = tid & 63;
  if (ln == 0) redm[wv] = m;
  __syncthreads();
  float bm = fmaxf(fmaxf(redm[0], redm[1]), fmaxf(redm[2], redm[3]));
  float s = 0.f;
  for (int t = t0 + tid; t < t1; t += 256) s += __expf(logit[t] - bm);
#pragma unroll
  for (int off = 32; off; off >>= 1) s += __shfl_xor(s, off, 64);
  if (ln == 0) reds[wv] = s;
  __syncthreads();
  float bs = reds[0] + reds[1] + reds[2] + reds[3];
  float r = __builtin_amdgcn_rcpf(bs);
  int per = (len + 3) >> 2;
  int a0 = t0 + ch * per;
  int a1 = min(t1, a0 + per);
  __shared__ float wsh[128];
  int h = tid * 2;
  float2 acc = make_float2(0.f, 0.f);
  for (int base = a0; base < a1; base += 128) {
    int cnt = min(128, a1 - base);
    __syncthreads();
    if (tid < cnt) wsh[tid] = __expf(logit[base + tid] - bm) * r;
    __syncthreads();
    for (int s2 = 0; s2 < cnt; ++s2) {
      float2 f = *(const float2*)(ast + (size_t)(base + s2) * HD + h);
      acc.x += wsh[s2] * f.x; acc.y += wsh[s2] * f.y;
    }
  }
  atomicAdd(&pool[b * 512 + h], acc.x);
  atomicAdd(&pool[b * 512 + h + 1], acc.y);
}

__global__ void pool_cfg_kernel(const float* __restrict__ feat, const float* __restrict__ logit,
                                const int* __restrict__ mask, const float* __restrict__ cptr,
                                float* __restrict__ pool) {
  int b = blockIdx.x, ch = blockIdx.y;       // 2 chunks x 128 n
  int tid = threadIdx.x;
  float cc = cptr[0];
  __shared__ float gsh[128];
  int n0 = ch * 128;
  if (tid < 128) {
    int n = n0 + tid;
    float g = fast_sigmoid(logit[b * 256 + n] + cc);
    gsh[tid] = mask[b * 256 + n] ? g : 0.f;
  }
  __syncthreads();
  int h = tid * 2;
  float2 acc = make_float2(0.f, 0.f);
  const float* fb = feat + ((size_t)b * 256 + n0) * HD + h;
#pragma unroll 4
  for (int s = 0; s < 128; ++s) {
    float2 f = *(const float2*)(fb + (size_t)s * HD);
    acc.x += gsh[s] * f.x; acc.y += gsh[s] * f.y;
  }
  atomicAdd(&pool[b * 512 + h], acc.x);
  atomicAdd(&pool[b * 512 + h + 1], acc.y);
}

// ============ fusion: concat @ W_fuse, no atomics ============
__global__ void fuse_partial_kernel(const float* __restrict__ pools,   // [3][128][512]
                                    const float* __restrict__ Wf,
                                    float* __restrict__ fpart) {       // [12][128][512]
  int bg = blockIdx.x, kc = blockIdx.y;
  int tid = threadIdx.x;
  int bq = tid >> 7, jt = tid & 127;
  __shared__ float psh[8][128];
  for (int idx = tid; idx < 8 * 128; idx += 256) {
    int bb = idx >> 7, kk = idx & 127;
    int i = kc * 128 + kk;
    psh[bb][kk] = pools[(size_t)(i >> 9) * 65536 + (size_t)(bg * 8 + bb) * 512 + (i & 511)];
  }
  __syncthreads();
  f32x4 acc[4];
#pragma unroll
  for (int bb = 0; bb < 4; ++bb) acc[bb] = (f32x4){0.f, 0.f, 0.f, 0.f};
  const float* wrow = Wf + (size_t)(kc * 128) * 512 + jt * 4;
#pragma unroll 4
  for (int k = 0; k < 128; ++k) {
    float4 wv = *(const float4*)(wrow + (size_t)k * 512);
#pragma unroll
    for (int bb = 0; bb < 4; ++bb) {
      float p = psh[bq * 4 + bb][k];
      acc[bb][0] += p * wv.x; acc[bb][1] += p * wv.y;
      acc[bb][2] += p * wv.z; acc[bb][3] += p * wv.w;
    }
  }
  float* dst = fpart + (size_t)kc * 65536 + (size_t)(bg * 8 + bq * 4) * 512 + jt * 4;
#pragma unroll
  for (int bb = 0; bb < 4; ++bb)
    *(f32x4*)(dst + (size_t)bb * 512) = acc[bb];
}

__global__ void finalize_kernel(const float* __restrict__ fpart, const float* __restrict__ bfuse,
                                float* __restrict__ out) {
  int idx = blockIdx.x * 256 + threadIdx.x;  // 65536
  float s = bfuse[idx & 511];
#pragma unroll
  for (int kc = 0; kc < 12; ++kc) s += fpart[(size_t)kc * 65536 + idx];
  out[idx] = fast_tanh(s);
}

// ============ workspace layout (bytes) ============
static constexpr size_t OFF_WB_TOK = 0;
static constexpr size_t OFF_WB_AST = 512 * 1024;
static constexpr size_t OFF_WB_CFG = 1024 * 1024;
static constexpr size_t OFF_ZERO   = 1536 * 1024;
static constexpr size_t OFF_LG_TOK = OFF_ZERO;                       // 65536 f32
static constexpr size_t OFF_LG_AST = OFF_LG_TOK + 65536 * 4;         // 40960 f32
static constexpr size_t OFF_LG_CFG = OFF_LG_AST + 40960 * 4;         // 32768 f32
static constexpr size_t OFF_POOLS  = OFF_LG_CFG + 32768 * 4;         // 3*65536 f32
static constexpr size_t OFF_SS     = OFF_POOLS + 3 * 65536 * 4;      // 128 i32
static constexpr size_t OFF_SE     = OFF_SS + 512;
static constexpr size_t ZERO_BYTES = OFF_SE + 512 - OFF_ZERO;
static constexpr size_t OFF_FPART  = OFF_SE + 512;                   // 12*65536 f32

extern "C" void kernel_launch(void* const* d_in, const int* in_sizes, int n_in,
                              void* d_out, int out_size, void* d_ws, size_t ws_size,
                              hipStream_t stream) {
  const float* tok_feat = (const float*)d_in[0];
  const float* ast_h    = (const float*)d_in[1];
  const float* cfg_feat = (const float*)d_in[2];
  const float* W_tok = (const float*)d_in[3];
  const float* b_tok = (const float*)d_in[4];
  const float* v_tok = (const float*)d_in[5];
  const float* W_ast = (const float*)d_in[7];
  const float* b_ast = (const float*)d_in[8];
  const float* v_ast = (const float*)d_in[9];
  const float* W_cfg = (const float*)d_in[11];
  const float* b_cfg = (const float*)d_in[12];
  const float* v_cfg = (const float*)d_in[13];
  const float* c_cfg = (const float*)d_in[14];
  const float* W_fuse = (const float*)d_in[15];
  const float* b_fuse = (const float*)d_in[16];
  const int* tok_len  = (const int*)d_in[17];
  const int* node_seg = (const int*)d_in[18];
  const int* cfg_mask = (const int*)d_in[19];

  const int M_tok = in_sizes[0] / HD;   // 65536
  const int T_ast = in_sizes[1] / HD;   // 40960
  const int M_cfg = in_sizes[2] / HD;   // 32768

  char* ws = (char*)d_ws;
  unsigned short* wbAll = (unsigned short*)(ws + OFF_WB_TOK);
  unsigned short* wbTok = (unsigned short*)(ws + OFF_WB_TOK);
  unsigned short* wbAst = (unsigned short*)(ws + OFF_WB_AST);
  unsigned short* wbCfg = (unsigned short*)(ws + OFF_WB_CFG);
  float* lgTok = (float*)(ws + OFF_LG_TOK);
  float* lgAst = (float*)(ws + OFF_LG_AST);
  float* lgCfg = (float*)(ws + OFF_LG_CFG);
  float* pools = (float*)(ws + OFF_POOLS);
  int*   ss    = (int*)(ws + OFF_SS);
  int*   se    = (int*)(ws + OFF_SE);
  float* fpart = (float*)(ws + OFF_FPART);

  // zero accumulators (logits, pools, seg bounds)
  hipMemsetAsync(ws + OFF_ZERO, 0, ZERO_BYTES, stream);

  // W -> bf16 fragment layout (all 3 matrices, one dispatch)
  prep_w_kernel<<<192, 256, 0, stream>>>(W_tok, W_ast, W_cfg, wbAll);
  seg_bounds_kernel<<<(T_ast + 255) / 256, 256, 0, stream>>>(node_seg, ss, se, T_ast);

  // ---- token modality (pool right after gemm: tok_feat still L3-resident)
  gemm_logit_kernel<<<M_tok / 64, 512, 0, stream>>>(tok_feat, wbTok, b_tok, v_tok, lgTok);
  pool_tok_kernel<<<dim3(128, 4), 256, 0, stream>>>(tok_feat, lgTok, tok_len, pools + 0 * 65536);

  // ---- AST modality
  gemm_logit_kernel<<<T_ast / 64, 512, 0, stream>>>(ast_h, wbAst, b_ast, v_ast, lgAst);
  pool_ast_kernel<<<dim3(128, 4), 256, 0, stream>>>(ast_h, lgAst, ss, se, pools + 1 * 65536);

  // ---- CFG modality
  gemm_logit_kernel<<<M_cfg / 64, 512, 0, stream>>>(cfg_feat, wbCfg, b_cfg, v_cfg, lgCfg);
  pool_cfg_kernel<<<dim3(128, 2), 256, 0, stream>>>(cfg_feat, lgCfg, cfg_mask, c_cfg, pools + 2 * 65536);

  // ---- fusion
  fuse_partial_kernel<<<dim3(16, 12), 256, 0, stream>>>(pools, W_fuse, fpart);
  finalize_kernel<<<256, 256, 0, stream>>>(fpart, b_fuse, (float*)d_out);
}